// Round 6
// baseline (169.989 us; speedup 1.0000x reference)
//
#include <hip/hip_runtime.h>
#include <math.h>

#define NPTS   4096
#define NB     8
#define NPTOT  (NB * NPTS)                 // 32768
#define ITILE  128                         // i-points per tile (2 blocks share a tile)
#define NTILE  (NPTOT / ITILE)             // 256 tiles
#define W      8                           // waves per block
#define BLKT   (W * 64)                    // 512 threads
#define JHALF  (NPTS / 2)                  // 2048 j-points per block
#define JCH    (JHALF / W)                 // 256 j per wave
#define INV_H2 (1.0f / (0.03f * 0.03f))
#define INFD   3.0e38f

__device__ __forceinline__ float med3f(float a, float b, float c) {
#if defined(__has_builtin)
#if __has_builtin(__builtin_amdgcn_fmed3f)
  return __builtin_amdgcn_fmed3f(a, b, c);
#else
  return fminf(c, fmaxf(a, b));
#endif
#else
  return fminf(c, fmaxf(a, b));
#endif
}

// lowest-4 (ascending) of two ascending 4-lists.
__device__ __forceinline__ float4 merge4(float4 A, float4 B) {
  float L0 = fminf(A.x, B.w), L1 = fminf(A.y, B.z);
  float L2 = fminf(A.z, B.y), L3 = fminf(A.w, B.x);
  float e0 = fminf(L0, L2), e2 = fmaxf(L0, L2);
  float e1 = fminf(L1, L3), e3 = fmaxf(L1, L3);
  return make_float4(fminf(e0, e1), fmaxf(e0, e1), fminf(e2, e3), fmaxf(e2, e3));
}

// u-domain scan (u = ||q||^2 - 2 p.q; monotone in d, ||p||^2 added at the end).
// Per j: 1 broadcast ds_read_b128 + 14 VALU (6 fma + 8 ladder) for 128 pairs.
template <bool CHECK>
__device__ __forceinline__ void scan(const float4* __restrict__ sP, int lo, int hi,
                                     int ls0, int ls1,
                                     float mx0, float my0, float mz0,
                                     float mx1, float my1, float mz1,
                                     float& r0, float& r1, float& r2, float& r3,
                                     float& s0, float& s1, float& s2, float& s3) {
#pragma unroll 4
  for (int j = lo; j < hi; ++j) {
    float4 q = sP[j];                       // wave-uniform -> broadcast, conflict-free
    float u0 = fmaf(mx0, q.x, fmaf(my0, q.y, fmaf(mz0, q.z, q.w)));
    float u1 = fmaf(mx1, q.x, fmaf(my1, q.y, fmaf(mz1, q.z, q.w)));
    if (CHECK) {                            // only the wave whose chunk holds the tile
      u0 = (j == ls0) ? INFD : u0;
      u1 = (j == ls1) ? INFD : u1;
    }
    r3 = med3f(r2, u0, r3); r2 = med3f(r1, u0, r2);
    r1 = med3f(r0, u0, r1); r0 = fminf(r0, u0);
    s3 = med3f(s2, u1, s3); s2 = med3f(s1, u1, s2);
    s1 = med3f(s0, u1, s1); s0 = fminf(s0, u1);
  }
}

__global__ __launch_bounds__(BLKT)
void repulsion_kernel(const float* __restrict__ pc, float4* __restrict__ part,
                      int* __restrict__ tickets, float* __restrict__ out) {
  __shared__ float4 sP[JHALF];              // 32 KB staged j-half (x,y,z,||q||^2)
  __shared__ float4 cand[W * ITILE];        // 16 KB per-wave partial lists
  __shared__ float  sqv[ITILE];             // 512 B ||p_i||^2
  __shared__ int    lastflag;

  const int blk  = blockIdx.x;
  const int tile = blk >> 1;                // 0..255
  const int half = blk & 1;                 // j-half
  const int b    = tile >> 5;               // batch
  const int g    = tile & 31;               // i-tile within batch
  const int tid  = threadIdx.x;
  const int w    = tid >> 6;
  const int lane = tid & 63;
  const float* base = pc + (size_t)b * NPTS * 3;

  // Stage j-half: 512 threads x 3 float4 -> 4 points each (2048 points, 24 KB in).
  {
    const float4* pcv = (const float4*)base + half * (JHALF * 3 / 4);
    float4 a = pcv[3 * tid + 0];
    float4 c = pcv[3 * tid + 1];
    float4 e = pcv[3 * tid + 2];
    float x0 = a.x, y0 = a.y, z0 = a.z;
    float x1 = a.w, y1 = c.x, z1 = c.y;
    float x2 = c.z, y2 = c.w, z2 = e.x;
    float x3 = e.y, y3 = e.z, z3 = e.w;
    sP[4 * tid + 0] = make_float4(x0, y0, z0, fmaf(x0, x0, fmaf(y0, y0, z0 * z0)));
    sP[4 * tid + 1] = make_float4(x1, y1, z1, fmaf(x1, x1, fmaf(y1, y1, z1 * z1)));
    sP[4 * tid + 2] = make_float4(x2, y2, z2, fmaf(x2, x2, fmaf(y2, y2, z2 * z2)));
    sP[4 * tid + 3] = make_float4(x3, y3, z3, fmaf(x3, x3, fmaf(y3, y3, z3 * z3)));
  }

  // i-points (same 128 for every wave of the block), premultiplied -2*p.
  const int gi0 = g * ITILE + lane;         // batch-local index of lane's i-points
  const int gi1 = gi0 + 64;
  float x0 = base[3 * gi0 + 0], y0 = base[3 * gi0 + 1], z0 = base[3 * gi0 + 2];
  float x1 = base[3 * gi1 + 0], y1 = base[3 * gi1 + 1], z1 = base[3 * gi1 + 2];
  const float mx0 = -2.0f * x0, my0 = -2.0f * y0, mz0 = -2.0f * z0;
  const float mx1 = -2.0f * x1, my1 = -2.0f * y1, mz1 = -2.0f * z1;
  if (w == 0) {
    sqv[lane]      = fmaf(x0, x0, fmaf(y0, y0, z0 * z0));
    sqv[lane + 64] = fmaf(x1, x1, fmaf(y1, y1, z1 * z1));
  }
  __syncthreads();

  // Scan this wave's 256-j chunk.
  float r0 = INFD, r1 = INFD, r2 = INFD, r3 = INFD;
  float s0 = INFD, s1 = INFD, s2 = INFD, s3 = INFD;
  const int lo  = w * JCH, hi = lo + JCH;
  const int sb  = g * ITILE - half * JHALF; // self-span start in local j coords
  const int ls0 = sb + lane, ls1 = ls0 + 64;
  // 128-aligned 128-span never crosses a 256 boundary -> at most one wave checks.
  const bool chk = (sb >= 0) && (sb < JHALF) && (w == (sb >> 8));
  if (chk) scan<true >(sP, lo, hi, ls0, ls1, mx0, my0, mz0, mx1, my1, mz1,
                       r0, r1, r2, r3, s0, s1, s2, s3);
  else     scan<false>(sP, lo, hi, ls0, ls1, mx0, my0, mz0, mx1, my1, mz1,
                       r0, r1, r2, r3, s0, s1, s2, s3);

  cand[w * ITILE + lane]      = make_float4(r0, r1, r2, r3);
  cand[w * ITILE + 64 + lane] = make_float4(s0, s1, s2, s3);
  __syncthreads();

  // Merge the 8 wave-lists per i-point; threads 0..127 own one i-point each.
  float4 R;
  if (tid < ITILE) {
    float4 L[W];
#pragma unroll
    for (int k = 0; k < W; ++k) L[k] = cand[k * ITILE + tid];
#pragma unroll
    for (int k = 0; k < 4; ++k) L[k] = merge4(L[2 * k], L[2 * k + 1]);
    L[0] = merge4(L[0], L[1]);
    L[1] = merge4(L[2], L[3]);
    R = merge4(L[0], L[1]);                 // sorted partial 4-list (u-domain)
    part[(size_t)blk * ITILE + tid] = R;    // publish this half's partial
  }

  // Last-block-merges: ticket per tile (zeroed by host-side memset each launch).
  __threadfence();                          // make part[] visible device-wide
  __syncthreads();
  if (tid == 0) lastflag = atomicAdd(&tickets[tile], 1);
  __syncthreads();
  if (lastflag != 1) return;                // first arrival exits; second merges

  __threadfence();                          // acquire partner's part[] writes
  if (tid < ITILE) {
    float4 O = part[(size_t)(tile * 2 + (1 - half)) * ITILE + tid];
    float4 A = merge4(R, O);                // need only the 4-smallest SET:
    float f0 = A.x, f1 = A.y, f2 = A.z, f3 = A.w;
    const float sqi = sqv[tid];
    float su = 0.0f;
    float m;
    // d = u + ||p||^2; clamp >= 0 (reference does maximum(dist,0));
    // cap at 0.5: weight underflows to exactly 0 there, and it guards INFD slots.
    m = fminf(fmaxf(f0 + sqi, 0.0f), 0.5f); su -= m * expf(-m * INV_H2);
    m = fminf(fmaxf(f1 + sqi, 0.0f), 0.5f); su -= m * expf(-m * INV_H2);
    m = fminf(fmaxf(f2 + sqi, 0.0f), 0.5f); su -= m * expf(-m * INV_H2);
    m = fminf(fmaxf(f3 + sqi, 0.0f), 0.5f); su -= m * expf(-m * INV_H2);

    for (int off = 32; off > 0; off >>= 1) su += __shfl_down(su, off);
    if ((tid & 63) == 0) atomicAdd(out, su);   // 2 atomics per tile
  }
}

extern "C" void kernel_launch(void* const* d_in, const int* in_sizes, int n_in,
                              void* d_out, int out_size, void* d_ws, size_t ws_size,
                              hipStream_t stream) {
  const float* pc = (const float*)d_in[0];
  float* out = (float*)d_out;
  // ws layout: [0, 1 MB): partials (512 * 128 float4); then 256 tickets (1 KB).
  float4* part   = (float4*)d_ws;
  int*    tickets = (int*)((char*)d_ws + (size_t)2 * NTILE * ITILE * sizeof(float4));
  hipMemsetAsync(out, 0, sizeof(float), stream);
  hipMemsetAsync(tickets, 0, NTILE * sizeof(int), stream);
  repulsion_kernel<<<dim3(2 * NTILE), dim3(BLKT), 0, stream>>>(pc, part, tickets, out);
}

// Round 7
// 87.151 us; speedup vs baseline: 1.9505x; 1.9505x over previous
//
#include <hip/hip_runtime.h>
#include <math.h>

#define NPTS   4096
#define NB     8
#define ITILE  128                        // i-points per block (64 lanes x IT=2)
#define NTPB   (NPTS / ITILE)             // 32 i-tiles per batch
#define W      8                          // waves per block
#define BLKT   (W * 64)                   // 512 threads
#define JCH    (NPTS / W)                 // 512 j per wave
#define INV_H2 (1.0f / (0.03f * 0.03f))
#define INFD   3.0e38f

__device__ __forceinline__ float med3f(float a, float b, float c) {
#if defined(__has_builtin)
#if __has_builtin(__builtin_amdgcn_fmed3f)
  return __builtin_amdgcn_fmed3f(a, b, c);
#else
  return fminf(c, fmaxf(a, b));
#endif
#else
  return fminf(c, fmaxf(a, b));
#endif
}

// lowest-4 (ascending) of two ascending 4-lists.
__device__ __forceinline__ float4 merge4(float4 A, float4 B) {
  float L0 = fminf(A.x, B.w), L1 = fminf(A.y, B.z);
  float L2 = fminf(A.z, B.y), L3 = fminf(A.w, B.x);
  float e0 = fminf(L0, L2), e2 = fmaxf(L0, L2);
  float e1 = fminf(L1, L3), e3 = fmaxf(L1, L3);
  return make_float4(fminf(e0, e1), fmaxf(e0, e1), fminf(e2, e3), fmaxf(e2, e3));
}

// u-domain scan (u = ||q||^2 - 2 p.q; monotone in d, ||p_i||^2 added at the end).
// Loads grouped 4-ahead so >=4 ds_reads stay in flight (R6's VGPR=40 starvation fix).
// Segment bounds are multiples of 4 by construction (lo/s0 multiples of 128).
template <bool CHECK>
__device__ __forceinline__ void scan(const float4* __restrict__ sP, int lo, int hi,
                                     int ls0, int ls1,
                                     float mx0, float my0, float mz0,
                                     float mx1, float my1, float mz1,
                                     float& r0, float& r1, float& r2, float& r3,
                                     float& s0, float& s1, float& s2, float& s3) {
  for (int j = lo; j < hi; j += 4) {
    float4 qa = sP[j + 0];                // broadcast (wave-uniform addr)
    float4 qb = sP[j + 1];
    float4 qc = sP[j + 2];
    float4 qd = sP[j + 3];
#pragma unroll
    for (int k = 0; k < 4; ++k) {
      float4 q = (k == 0) ? qa : (k == 1) ? qb : (k == 2) ? qc : qd;
      float u0 = fmaf(mx0, q.x, fmaf(my0, q.y, fmaf(mz0, q.z, q.w)));
      float u1 = fmaf(mx1, q.x, fmaf(my1, q.y, fmaf(mz1, q.z, q.w)));
      if (CHECK) {
        u0 = ((j + k) == ls0) ? INFD : u0;
        u1 = ((j + k) == ls1) ? INFD : u1;
      }
      r3 = med3f(r2, u0, r3); r2 = med3f(r1, u0, r2);
      r1 = med3f(r0, u0, r1); r0 = fminf(r0, u0);
      s3 = med3f(s2, u1, s3); s2 = med3f(s1, u1, s2);
      s1 = med3f(s0, u1, s1); s0 = fminf(s0, u1);
    }
  }
}

__global__ __launch_bounds__(BLKT)
void repulsion_kernel(const float* __restrict__ pc, float* __restrict__ out) {
  __shared__ float4 sP[NPTS];               // 64 KB (x,y,z,||q||^2)
  __shared__ float4 cand[W * ITILE];        // 16 KB -> 80 KB total, 2 blocks/CU cap

  const int blk  = blockIdx.x;
  const int b    = blk >> 5;                // batch
  const int g    = blk & 31;                // i-tile within batch
  const int tid  = threadIdx.x;
  const int w    = tid >> 6;
  const int lane = tid & 63;
  const float* base = pc + (size_t)b * NPTS * 3;
  const float4* pcv = (const float4*)base;

  // Stage all 4096 points: 2 rounds x (3 float4 loads -> 4 float4 LDS writes).
#pragma unroll
  for (int r = 0; r < 2; ++r) {
    int t = tid + r * BLKT;                 // 0..1023 triplet groups
    float4 a = pcv[3 * t + 0];
    float4 c = pcv[3 * t + 1];
    float4 e = pcv[3 * t + 2];
    float x0 = a.x, y0 = a.y, z0 = a.z;
    float x1 = a.w, y1 = c.x, z1 = c.y;
    float x2 = c.z, y2 = c.w, z2 = e.x;
    float x3 = e.y, y3 = e.z, z3 = e.w;
    sP[4 * t + 0] = make_float4(x0, y0, z0, fmaf(x0, x0, fmaf(y0, y0, z0 * z0)));
    sP[4 * t + 1] = make_float4(x1, y1, z1, fmaf(x1, x1, fmaf(y1, y1, z1 * z1)));
    sP[4 * t + 2] = make_float4(x2, y2, z2, fmaf(x2, x2, fmaf(y2, y2, z2 * z2)));
    sP[4 * t + 3] = make_float4(x3, y3, z3, fmaf(x3, x3, fmaf(y3, y3, z3 * z3)));
  }
  __syncthreads();

  // This lane's two i-points (batch-local indices; sP holds them).
  const int gi0 = g * ITILE + lane;
  const int gi1 = gi0 + 64;
  float4 p0 = sP[gi0];
  float4 p1 = sP[gi1];
  const float mx0 = -2.0f * p0.x, my0 = -2.0f * p0.y, mz0 = -2.0f * p0.z;
  const float mx1 = -2.0f * p1.x, my1 = -2.0f * p1.y, mz1 = -2.0f * p1.z;

  float r0 = INFD, r1 = INFD, r2 = INFD, r3 = INFD;
  float s0 = INFD, s1 = INFD, s2 = INFD, s3 = INFD;

  const int lo = w * JCH, hi = lo + JCH;
  const int selfwave = g >> 2;              // [g*128, g*128+128) lies in one 512-chunk
  if (w == selfwave) {
    const int s0i = g * ITILE;
    scan<false>(sP, lo, s0i, gi0, gi1, mx0, my0, mz0, mx1, my1, mz1,
                r0, r1, r2, r3, s0, s1, s2, s3);
    scan<true >(sP, s0i, s0i + ITILE, gi0, gi1, mx0, my0, mz0, mx1, my1, mz1,
                r0, r1, r2, r3, s0, s1, s2, s3);
    scan<false>(sP, s0i + ITILE, hi, gi0, gi1, mx0, my0, mz0, mx1, my1, mz1,
                r0, r1, r2, r3, s0, s1, s2, s3);
  } else {
    scan<false>(sP, lo, hi, gi0, gi1, mx0, my0, mz0, mx1, my1, mz1,
                r0, r1, r2, r3, s0, s1, s2, s3);
  }

  cand[w * ITILE + lane]      = make_float4(r0, r1, r2, r3);
  cand[w * ITILE + 64 + lane] = make_float4(s0, s1, s2, s3);
  __syncthreads();

  // Merge the 8 wave-lists per i-point; threads 0..127 own one i-point each.
  if (tid < ITILE) {
    float4 L[W];
#pragma unroll
    for (int k = 0; k < W; ++k) L[k] = cand[k * ITILE + tid];
#pragma unroll
    for (int k = 0; k < 4; ++k) L[k] = merge4(L[2 * k], L[2 * k + 1]);
    L[0] = merge4(L[0], L[1]);
    L[1] = merge4(L[2], L[3]);
    float4 F = merge4(L[0], L[1]);          // 4 smallest u, ascending

    const float sqi = sP[g * ITILE + tid].w;
    float su = 0.0f;
    float m;
    // d = u + ||p_i||^2; clamp >=0 (reference's maximum(dist,0)); cap 0.5:
    // weight exp(-0.5/9e-4) underflows to exactly 0 in f32 (matches reference).
    m = fminf(fmaxf(F.x + sqi, 0.0f), 0.5f); su -= m * expf(-m * INV_H2);
    m = fminf(fmaxf(F.y + sqi, 0.0f), 0.5f); su -= m * expf(-m * INV_H2);
    m = fminf(fmaxf(F.z + sqi, 0.0f), 0.5f); su -= m * expf(-m * INV_H2);
    m = fminf(fmaxf(F.w + sqi, 0.0f), 0.5f); su -= m * expf(-m * INV_H2);

    for (int off = 32; off > 0; off >>= 1) su += __shfl_down(su, off);
    if ((tid & 63) == 0) atomicAdd(out, su);  // 2 atomics per block
  }
}

extern "C" void kernel_launch(void* const* d_in, const int* in_sizes, int n_in,
                              void* d_out, int out_size, void* d_ws, size_t ws_size,
                              hipStream_t stream) {
  const float* pc = (const float*)d_in[0];
  float* out = (float*)d_out;
  hipMemsetAsync(out, 0, sizeof(float), stream);
  repulsion_kernel<<<dim3(NB * NTPB), dim3(BLKT), 0, stream>>>(pc, out);
}